// Round 1
// baseline (36705.844 us; speedup 1.0000x reference)
//
#include <hip/hip_runtime.h>
#include <math.h>

// Problem constants
#define NS 4096      // N stocks
#define DIM 512      // D
#define NH 8         // heads
#define HD 64        // head dim
#define M2 4098      // N + 2 nodes
#define KKEEP 2048u  // top-k keep

// Output layout (floats): final_out | raw_scores | gate_mean | attn_mean
#define OUT_F 0
#define OUT_R 2097152          // 4096*512
#define OUT_G 18882560         // + 4096*4098
#define OUT_A 18882561

__device__ __forceinline__ float sigmoidf_(float x) { return 1.0f / (1.0f + __expf(-x)); }

// ---------------- regime_mod = sigmoid([zp,zs] @ Wg.T + bg) ----------------
__global__ __launch_bounds__(256) void regime_kernel(
    const float* __restrict__ zp, const float* __restrict__ zs,
    const float* __restrict__ Wg, const float* __restrict__ bg,
    float* __restrict__ regime) {
  __shared__ float zc[1024];
  int t = threadIdx.x;
  for (int i = t; i < 512; i += 256) { zc[i] = zp[i]; zc[512 + i] = zs[i]; }
  __syncthreads();
  for (int j = t; j < 512; j += 256) {
    const float4* w = (const float4*)(Wg + (size_t)j * 1024);
    float acc = 0.f;
    #pragma unroll 8
    for (int i = 0; i < 256; i++) {
      float4 wv = w[i];
      acc += wv.x * zc[4*i] + wv.y * zc[4*i+1] + wv.z * zc[4*i+2] + wv.w * zc[4*i+3];
    }
    regime[j] = sigmoidf_(acc + bg[j]);
  }
}

// ---------------- nodes = concat(zp, zs, stock_feats) ----------------
__global__ __launch_bounds__(256) void build_nodes(
    const float* __restrict__ zp, const float* __restrict__ zs,
    const float* __restrict__ sf, float* __restrict__ nodes) {
  int idx = blockIdx.x * 256 + threadIdx.x;
  int m = idx >> 9, c = idx & 511;
  float v;
  if (m == 0) v = zp[c];
  else if (m == 1) v = zs[c];
  else v = sf[(size_t)(m - 2) * 512 + c];
  nodes[idx] = v;
}

// ---------------- C[m,j] = (sum_k A[m,k]*B[j,k] + bias[j]) * cscale[j] ----------------
// 64x64 tile, 256 threads, 4x4 per thread, K-step 32
__global__ __launch_bounds__(256) void gemm_bt(
    const float* __restrict__ A, const float* __restrict__ B,
    const float* __restrict__ bias, const float* __restrict__ cscale,
    float* __restrict__ C, int M, int Nc, int K) {
  __shared__ float As[32][68];
  __shared__ float Bs[32][68];
  const int t = threadIdx.x;
  const int bm = blockIdx.y * 64, bj = blockIdx.x * 64;
  const int tr = (t >> 4) * 4, tc = (t & 15) * 4;
  float acc[4][4] = {};
  for (int k0 = 0; k0 < K; k0 += 32) {
    #pragma unroll
    for (int i = 0; i < 2; i++) {
      int idx = t + i * 256;      // float4 index 0..511 over 64x32 tile
      int r = idx >> 3;
      int c = (idx & 7) * 4;
      float4 av = make_float4(0.f, 0.f, 0.f, 0.f);
      float4 bv = make_float4(0.f, 0.f, 0.f, 0.f);
      if (bm + r < M)  av = *(const float4*)(A + (size_t)(bm + r) * K + k0 + c);
      if (bj + r < Nc) bv = *(const float4*)(B + (size_t)(bj + r) * K + k0 + c);
      As[c][r] = av.x; As[c+1][r] = av.y; As[c+2][r] = av.z; As[c+3][r] = av.w;
      Bs[c][r] = bv.x; Bs[c+1][r] = bv.y; Bs[c+2][r] = bv.z; Bs[c+3][r] = bv.w;
    }
    __syncthreads();
    #pragma unroll
    for (int kk = 0; kk < 32; kk++) {
      float4 av = *(const float4*)&As[kk][tr];
      float4 bv = *(const float4*)&Bs[kk][tc];
      acc[0][0] += av.x*bv.x; acc[0][1] += av.x*bv.y; acc[0][2] += av.x*bv.z; acc[0][3] += av.x*bv.w;
      acc[1][0] += av.y*bv.x; acc[1][1] += av.y*bv.y; acc[1][2] += av.y*bv.z; acc[1][3] += av.y*bv.w;
      acc[2][0] += av.z*bv.x; acc[2][1] += av.z*bv.y; acc[2][2] += av.z*bv.z; acc[2][3] += av.z*bv.w;
      acc[3][0] += av.w*bv.x; acc[3][1] += av.w*bv.y; acc[3][2] += av.w*bv.z; acc[3][3] += av.w*bv.w;
    }
    __syncthreads();
  }
  float4 bsv = make_float4(0.f, 0.f, 0.f, 0.f);
  float4 csv = make_float4(1.f, 1.f, 1.f, 1.f);
  if (bias)   bsv = *(const float4*)(bias + bj + tc);
  if (cscale) csv = *(const float4*)(cscale + bj + tc);
  #pragma unroll
  for (int i = 0; i < 4; i++) {
    int m = bm + tr + i;
    if (m < M) {
      float4 o;
      o.x = (acc[i][0] + bsv.x) * csv.x;
      o.y = (acc[i][1] + bsv.y) * csv.y;
      o.z = (acc[i][2] + bsv.z) * csv.z;
      o.w = (acc[i][3] + bsv.w) * csv.w;
      *(float4*)(C + (size_t)m * Nc + bj + tc) = o;
    }
  }
}

// ---------------- attention: one block per stock row n, loop heads ----------------
// scores row in LDS, exact rank-2048 threshold via 4-pass radix select,
// masked softmax, PV, and accumulation of raw/attn head means.
__global__ __launch_bounds__(256) void attn_kernel(
    const float* __restrict__ q, const float* __restrict__ k,
    const float* __restrict__ v, float* __restrict__ attn_out,
    float* __restrict__ raw_out, float* __restrict__ attn_mean_out) {
  const int n = blockIdx.x, t = threadIdx.x;
  __shared__ float s_row[M2];
  __shared__ float rawacc[M2];
  __shared__ float attnacc[M2];
  __shared__ float q_l[HD];
  __shared__ unsigned hist[256];
  __shared__ unsigned s_selb, s_selgt;
  float* redf = (float*)hist;

  for (int h = 0; h < NH; h++) {
    if (t < HD) q_l[t] = q[(size_t)n * DIM + h * HD + t];
    __syncthreads();

    // ---- scores + raw accumulation ----
    for (int m = t; m < M2; m += 256) {
      const float4* kr = (const float4*)(k + (size_t)m * DIM + h * HD);
      float acc = 0.f;
      #pragma unroll
      for (int i = 0; i < 16; i++) {
        float4 kv = kr[i];
        acc += kv.x * q_l[4*i] + kv.y * q_l[4*i+1] + kv.z * q_l[4*i+2] + kv.w * q_l[4*i+3];
      }
      float s = acc * 0.125f;   // 1/sqrt(64)
      s_row[m] = s;
      float r = s * 0.125f;     // /8 heads
      if (h == 0) rawacc[m] = r; else rawacc[m] += r;
    }
    __syncthreads();

    // ---- radix select: rank-2048 largest among s_row[2..4097] ----
    unsigned prefix = 0, pmask = 0, k_rem = KKEEP;
    for (int pass = 0; pass < 4; pass++) {
      int shift = 24 - pass * 8;
      hist[t] = 0;
      __syncthreads();
      #pragma unroll
      for (int j = 0; j < 16; j++) {
        int m = 2 + t + j * 256;
        unsigned u = __float_as_uint(s_row[m]);
        unsigned key = u ^ (0x80000000u | (unsigned)((int)u >> 31));
        if ((key & pmask) == prefix) atomicAdd(&hist[(key >> shift) & 255u], 1u);
      }
      __syncthreads();
      // suffix sums (hist[t] = count of active with byte >= t)
      for (int off = 1; off < 256; off <<= 1) {
        unsigned add = (t + off < 256) ? hist[t + off] : 0u;
        __syncthreads();
        hist[t] += add;
        __syncthreads();
      }
      unsigned sfx = hist[t];
      unsigned nxt = (t < 255) ? hist[t + 1] : 0u;
      if (sfx >= k_rem && nxt < k_rem) { s_selb = (unsigned)t; s_selgt = nxt; }
      __syncthreads();
      prefix |= s_selb << shift;
      pmask |= 255u << shift;
      k_rem -= s_selgt;
      __syncthreads();
    }
    unsigned tu = (prefix & 0x80000000u) ? (prefix ^ 0x80000000u) : ~prefix;
    float thr = __uint_as_float(tu);

    // ---- mask stocks below threshold ----
    for (int m = 2 + t; m < M2; m += 256)
      if (s_row[m] < thr) s_row[m] = -1e9f;
    __syncthreads();

    // ---- softmax ----
    float lmax = -3.0e38f;
    for (int m = t; m < M2; m += 256) lmax = fmaxf(lmax, s_row[m]);
    redf[t] = lmax;
    __syncthreads();
    for (int off = 128; off > 0; off >>= 1) {
      if (t < off) redf[t] = fmaxf(redf[t], redf[t + off]);
      __syncthreads();
    }
    float rmax = redf[0];
    __syncthreads();
    float lsum = 0.f;
    for (int m = t; m < M2; m += 256) {
      float e = __expf(s_row[m] - rmax);
      s_row[m] = e;
      lsum += e;
    }
    redf[t] = lsum;
    __syncthreads();
    for (int off = 128; off > 0; off >>= 1) {
      if (t < off) redf[t] += redf[t + off];
      __syncthreads();
    }
    float invZ = 1.0f / redf[0];
    __syncthreads();
    for (int m = t; m < M2; m += 256) {
      float p = s_row[m] * invZ;
      s_row[m] = p;
      float a = p * 0.125f;
      if (h == 0) attnacc[m] = a; else attnacc[m] += a;
    }
    __syncthreads();

    // ---- PV: out[n,h,d] = sum_m p[m] * v[m,h,d] ----
    int d = t & 63, part = t >> 6;
    float acc = 0.f;
    for (int m = part; m < M2; m += 4)
      acc += s_row[m] * v[(size_t)m * DIM + h * HD + d];
    redf[t] = acc;
    __syncthreads();
    if (part == 0)
      attn_out[(size_t)n * DIM + h * HD + d] = redf[d] + redf[64 + d] + redf[128 + d] + redf[192 + d];
    __syncthreads();
  }

  // ---- write head means ----
  for (int m = t; m < M2; m += 256) {
    raw_out[(size_t)n * M2 + m] = rawacc[m];
    attn_mean_out[(size_t)n * M2 + m] = attnacc[m];
  }
}

// ---------------- concat(stock_feats, proj) ----------------
__global__ __launch_bounds__(256) void cat_kernel(
    const float* __restrict__ sf, const float* __restrict__ pj, float* __restrict__ cat) {
  int idx = blockIdx.x * 256 + threadIdx.x;
  int n = idx >> 10, c = idx & 1023;
  cat[idx] = (c < 512) ? sf[(size_t)n * 512 + c] : pj[(size_t)n * 512 + (c - 512)];
}

// ---------------- gate, residual, RMSNorm, gate partial sums ----------------
__global__ __launch_bounds__(256) void final_kernel(
    const float* __restrict__ sf, const float* __restrict__ pj,
    const float* __restrict__ gl, const float* __restrict__ norm_w,
    float* __restrict__ outf, float* __restrict__ gpart) {
  int n = blockIdx.x, t = threadIdx.x;
  __shared__ float red[256];
  size_t base = (size_t)n * 512;
  float g0 = sigmoidf_(gl[base + t]);
  float g1 = sigmoidf_(gl[base + 256 + t]);
  float x0 = sf[base + t], x1 = sf[base + 256 + t];
  float p0 = pj[base + t], p1 = pj[base + 256 + t];
  float gr0 = x0 + g0 * p0, gr1 = x1 + g1 * p1;

  red[t] = g0 + g1;
  __syncthreads();
  for (int off = 128; off > 0; off >>= 1) {
    if (t < off) red[t] += red[t + off];
    __syncthreads();
  }
  if (t == 0) gpart[n] = red[0];
  __syncthreads();

  red[t] = gr0 * gr0 + gr1 * gr1;
  __syncthreads();
  for (int off = 128; off > 0; off >>= 1) {
    if (t < off) red[t] += red[t + off];
    __syncthreads();
  }
  float rms = rsqrtf(red[0] * (1.0f / 512.0f) + 1e-6f);
  outf[base + t] = gr0 * rms * norm_w[t];
  outf[base + 256 + t] = gr1 * rms * norm_w[256 + t];
}

__global__ __launch_bounds__(256) void gate_reduce(
    const float* __restrict__ gpart, float* __restrict__ out_scalar) {
  __shared__ float red[256];
  int t = threadIdx.x;
  float s = 0.f;
  for (int i = t; i < 4096; i += 256) s += gpart[i];
  red[t] = s;
  __syncthreads();
  for (int off = 128; off > 0; off >>= 1) {
    if (t < off) red[t] += red[t + off];
    __syncthreads();
  }
  if (t == 0) out_scalar[0] = red[0] * (1.0f / (4096.0f * 512.0f));
}

extern "C" void kernel_launch(void* const* d_in, const int* in_sizes, int n_in,
                              void* d_out, int out_size, void* d_ws, size_t ws_size,
                              hipStream_t stream) {
  const float* sf  = (const float*)d_in[0];
  const float* zp  = (const float*)d_in[1];
  const float* zs  = (const float*)d_in[2];
  const float* Wq  = (const float*)d_in[3];
  const float* Wk  = (const float*)d_in[4];
  const float* Wv  = (const float*)d_in[5];
  const float* Wg  = (const float*)d_in[6];
  const float* bg  = (const float*)d_in[7];
  const float* Wag = (const float*)d_in[8];
  const float* bag = (const float*)d_in[9];
  const float* nw  = (const float*)d_in[10];
  const float* Wo  = (const float*)d_in[11];
  const float* bo  = (const float*)d_in[12];

  float* out  = (float*)d_out;
  float* outF = out + OUT_F;
  float* outR = out + OUT_R;
  float* outG = out + OUT_G;
  float* outA = out + OUT_A;

  // workspace layout (floats); total 12,590,592 floats ~ 48 MB
  float* ws     = (float*)d_ws;
  float* regime = ws;                    // 512
  float* nodes  = ws + 512;              // 4098*512
  float* qb     = ws + 2098688;          // 4096*512
  float* kb     = ws + 4195840;          // 4098*512
  float* vb     = ws + 6294016;          // 4098*512
  float* ao     = ws + 8392192;          // 4096*512
  float* pj     = ws + 10489344;         // 4096*512
  float* gpart  = ws + 12586496;         // 4096
  float* cat    = ws + 512;              // reuse nodes+q region (4096*1024)
  float* gl     = ws + 4195840;          // reuse k region (4096*512)

  regime_kernel<<<1, 256, 0, stream>>>(zp, zs, Wg, bg, regime);
  build_nodes<<<8196, 256, 0, stream>>>(zp, zs, sf, nodes);
  gemm_bt<<<dim3(8, 64), 256, 0, stream>>>(sf,    Wq, nullptr, regime, qb, 4096, 512, 512);
  gemm_bt<<<dim3(8, 65), 256, 0, stream>>>(nodes, Wk, nullptr, nullptr, kb, 4098, 512, 512);
  gemm_bt<<<dim3(8, 65), 256, 0, stream>>>(nodes, Wv, nullptr, nullptr, vb, 4098, 512, 512);
  attn_kernel<<<4096, 256, 0, stream>>>(qb, kb, vb, ao, outR, outA);
  gemm_bt<<<dim3(8, 64), 256, 0, stream>>>(ao, Wo, bo, nullptr, pj, 4096, 512, 512);
  cat_kernel<<<16384, 256, 0, stream>>>(sf, pj, cat);
  gemm_bt<<<dim3(8, 64), 256, 0, stream>>>(cat, Wag, bag, nullptr, gl, 4096, 512, 1024);
  final_kernel<<<4096, 256, 0, stream>>>(sf, pj, gl, nw, outF, gpart);
  gate_reduce<<<1, 256, 0, stream>>>(gpart, outG);
}

// Round 2
// 5026.204 us; speedup vs baseline: 7.3029x; 7.3029x over previous
//
#include <hip/hip_runtime.h>
#include <math.h>

// Problem constants
#define NS 4096      // N stocks
#define DIM 512      // D
#define NH 8         // heads
#define HD 64        // head dim
#define M2 4098      // N + 2 nodes
#define KTS 4100     // Kt padded row stride (floats)
#define KKEEP 2048u  // top-k keep

// Output layout (floats): final_out | raw_scores | gate_mean | attn_mean
#define OUT_F 0
#define OUT_R 2097152          // 4096*512
#define OUT_G 18882560         // + 4096*4098
#define OUT_A 18882561

__device__ __forceinline__ float sigmoidf_(float x) { return 1.0f / (1.0f + __expf(-x)); }

// ---------------- regime_mod = sigmoid([zp,zs] @ Wg.T + bg) ----------------
__global__ __launch_bounds__(256) void regime_kernel(
    const float* __restrict__ zp, const float* __restrict__ zs,
    const float* __restrict__ Wg, const float* __restrict__ bg,
    float* __restrict__ regime) {
  __shared__ float zc[1024];
  int t = threadIdx.x;
  for (int i = t; i < 512; i += 256) { zc[i] = zp[i]; zc[512 + i] = zs[i]; }
  __syncthreads();
  for (int j = t; j < 512; j += 256) {
    const float4* w = (const float4*)(Wg + (size_t)j * 1024);
    float acc = 0.f;
    #pragma unroll 8
    for (int i = 0; i < 256; i++) {
      float4 wv = w[i];
      acc += wv.x * zc[4*i] + wv.y * zc[4*i+1] + wv.z * zc[4*i+2] + wv.w * zc[4*i+3];
    }
    regime[j] = sigmoidf_(acc + bg[j]);
  }
}

// ---------------- nodes = concat(zp, zs, stock_feats) ----------------
__global__ __launch_bounds__(256) void build_nodes(
    const float* __restrict__ zp, const float* __restrict__ zs,
    const float* __restrict__ sf, float* __restrict__ nodes) {
  int idx = blockIdx.x * 256 + threadIdx.x;
  int m = idx >> 9, c = idx & 511;
  float v;
  if (m == 0) v = zp[c];
  else if (m == 1) v = zs[c];
  else v = sf[(size_t)(m - 2) * 512 + c];
  nodes[idx] = v;
}

// ---------------- C[m,j] = (sum_k A[m,k]*B[j,k] + bias[j]) * cscale[j] ----------------
// 64x64 tile, 256 threads, 4x4 per thread, K-step 32.
// transC: store C[j*ldc + m] (scalar) instead of C[m*ldc + j] (float4).
__global__ __launch_bounds__(256) void gemm_bt(
    const float* __restrict__ A, const float* __restrict__ B,
    const float* __restrict__ bias, const float* __restrict__ cscale,
    float* __restrict__ C, int M, int Nc, int K, int ldc, int transC) {
  __shared__ float As[32][68];
  __shared__ float Bs[32][68];
  const int t = threadIdx.x;
  const int bm = blockIdx.y * 64, bj = blockIdx.x * 64;
  const int tr = (t >> 4) * 4, tc = (t & 15) * 4;
  float acc[4][4] = {};
  for (int k0 = 0; k0 < K; k0 += 32) {
    #pragma unroll
    for (int i = 0; i < 2; i++) {
      int idx = t + i * 256;      // float4 index 0..511 over 64x32 tile
      int r = idx >> 3;
      int c = (idx & 7) * 4;
      float4 av = make_float4(0.f, 0.f, 0.f, 0.f);
      float4 bv = make_float4(0.f, 0.f, 0.f, 0.f);
      if (bm + r < M)  av = *(const float4*)(A + (size_t)(bm + r) * K + k0 + c);
      if (bj + r < Nc) bv = *(const float4*)(B + (size_t)(bj + r) * K + k0 + c);
      As[c][r] = av.x; As[c+1][r] = av.y; As[c+2][r] = av.z; As[c+3][r] = av.w;
      Bs[c][r] = bv.x; Bs[c+1][r] = bv.y; Bs[c+2][r] = bv.z; Bs[c+3][r] = bv.w;
    }
    __syncthreads();
    #pragma unroll
    for (int kk = 0; kk < 32; kk++) {
      float4 av = *(const float4*)&As[kk][tr];
      float4 bv = *(const float4*)&Bs[kk][tc];
      acc[0][0] += av.x*bv.x; acc[0][1] += av.x*bv.y; acc[0][2] += av.x*bv.z; acc[0][3] += av.x*bv.w;
      acc[1][0] += av.y*bv.x; acc[1][1] += av.y*bv.y; acc[1][2] += av.y*bv.z; acc[1][3] += av.y*bv.w;
      acc[2][0] += av.z*bv.x; acc[2][1] += av.z*bv.y; acc[2][2] += av.z*bv.z; acc[2][3] += av.z*bv.w;
      acc[3][0] += av.w*bv.x; acc[3][1] += av.w*bv.y; acc[3][2] += av.w*bv.z; acc[3][3] += av.w*bv.w;
    }
    __syncthreads();
  }
  float4 bsv = make_float4(0.f, 0.f, 0.f, 0.f);
  float4 csv = make_float4(1.f, 1.f, 1.f, 1.f);
  if (bias)   bsv = *(const float4*)(bias + bj + tc);
  if (cscale) csv = *(const float4*)(cscale + bj + tc);
  if (transC) {
    #pragma unroll
    for (int i = 0; i < 4; i++) {
      int m = bm + tr + i;
      if (m < M) {
        C[(size_t)(bj + tc + 0) * ldc + m] = (acc[i][0] + bsv.x) * csv.x;
        C[(size_t)(bj + tc + 1) * ldc + m] = (acc[i][1] + bsv.y) * csv.y;
        C[(size_t)(bj + tc + 2) * ldc + m] = (acc[i][2] + bsv.z) * csv.z;
        C[(size_t)(bj + tc + 3) * ldc + m] = (acc[i][3] + bsv.w) * csv.w;
      }
    }
  } else {
    #pragma unroll
    for (int i = 0; i < 4; i++) {
      int m = bm + tr + i;
      if (m < M) {
        float4 o;
        o.x = (acc[i][0] + bsv.x) * csv.x;
        o.y = (acc[i][1] + bsv.y) * csv.y;
        o.z = (acc[i][2] + bsv.z) * csv.z;
        o.w = (acc[i][3] + bsv.w) * csv.w;
        *(float4*)(C + (size_t)m * ldc + bj + tc) = o;
      }
    }
  }
}

// ---------------- attention: one block per stock row n; 8 waves = 8 heads ----------------
// Wave-synchronous per-head pipeline (no block barriers in hot path):
//   scores (Kt coalesced float4) -> exact rank-2048 radix select (wave shuffles)
//   -> mask -> softmax -> PV (float4, shuffle reduce).
// 3 block barriers total: for raw_scores and attn_mean cross-head reductions.
// Dynamic LDS: 8x4100 scores + 8x256 hist + 8x64 q + 8 invZ = 141,472 B.
#define SMEM_FLOATS (8*KTS + 8*256 + 8*64 + 8)

__global__ __launch_bounds__(512) void attn_kernel(
    const float* __restrict__ q, const float* __restrict__ kt,
    const float* __restrict__ vb, float* __restrict__ attn_out,
    float* __restrict__ raw_out, float* __restrict__ attn_mean_out) {
  extern __shared__ float smem[];
  float* srow_all = smem;                          // 8 x KTS
  unsigned* hist_all = (unsigned*)(smem + 8*KTS);  // 8 x 256
  float* q_all = smem + 8*KTS + 8*256;             // 8 x 64
  float* invZ_all = q_all + 8*64;                  // 8

  const int n = blockIdx.x, t = threadIdx.x;
  const int h = t >> 6, lane = t & 63;
  float* srow = srow_all + h * KTS;
  unsigned* hist = hist_all + h * 256;
  float* q_l = q_all + h * 64;

  // ---- load q_h (one coalesced load per wave) ----
  q_l[lane] = q[(size_t)n * DIM + h * HD + lane];

  // ---- scores: s[m] = 0.125 * sum_d q[d] * Kt[h*64+d][m] ----
  {
    const float* ktbase = kt + (size_t)h * 64 * KTS;
    for (int mb = 0; mb < M2; mb += 256) {
      int m0 = mb + 4 * lane;
      float ax = 0.f, ay = 0.f, az = 0.f, aw = 0.f;
      const float* kp = ktbase + m0;
      #pragma unroll 8
      for (int d = 0; d < 64; ++d) {
        float4 kv = *(const float4*)(kp + (size_t)d * KTS);
        float qd = q_l[d];
        ax += kv.x * qd; ay += kv.y * qd; az += kv.z * qd; aw += kv.w * qd;
      }
      if (m0 < M2) {
        srow[m0] = ax * 0.125f;
        if (m0 + 1 < M2) srow[m0 + 1] = ay * 0.125f;
        if (m0 + 2 < M2) srow[m0 + 2] = az * 0.125f;
        if (m0 + 3 < M2) srow[m0 + 3] = aw * 0.125f;
      }
    }
  }
  __syncthreads();

  // ---- raw_scores = mean over heads (pre-mask) ----
  for (int m = t; m < M2; m += 512) {
    float r = 0.f;
    #pragma unroll
    for (int hh = 0; hh < 8; ++hh) r += srow_all[hh * KTS + m];
    raw_out[(size_t)n * M2 + m] = r * 0.125f;
  }
  __syncthreads();

  // ---- exact rank-2048 threshold among stocks (m in [2,4098)) : wave radix select ----
  float thr;
  {
    unsigned prefix = 0, pmask = 0, k_rem = KKEEP;
    for (int pass = 0; pass < 4; ++pass) {
      int shift = 24 - pass * 8;
      hist[lane] = 0u; hist[lane + 64] = 0u; hist[lane + 128] = 0u; hist[lane + 192] = 0u;
      for (int j = 0; j < 64; ++j) {
        unsigned u = __float_as_uint(srow[2 + j * 64 + lane]);
        unsigned key = u ^ (0x80000000u | (unsigned)((int)u >> 31));
        if ((key & pmask) == prefix) atomicAdd(&hist[(key >> shift) & 255u], 1u);
      }
      unsigned c0 = hist[4*lane], c1 = hist[4*lane+1], c2 = hist[4*lane+2], c3 = hist[4*lane+3];
      unsigned lsum = c0 + c1 + c2 + c3;
      unsigned run = lsum;   // inclusive suffix sum over lanes
      #pragma unroll
      for (int off = 1; off < 64; off <<= 1) {
        unsigned o = __shfl_down(run, off, 64);
        if (lane + off < 64) run += o;
      }
      unsigned s0 = run, s1 = run - c0, s2 = s1 - c1, s3 = s2 - c2, s4 = s3 - c3;
      int which = -1;
      if      (s0 >= k_rem && s1 < k_rem) which = 0;
      else if (s1 >= k_rem && s2 < k_rem) which = 1;
      else if (s2 >= k_rem && s3 < k_rem) which = 2;
      else if (s3 >= k_rem && s4 < k_rem) which = 3;
      unsigned long long bal = __ballot(which >= 0);
      int src = (int)__ffsll((unsigned long long)bal) - 1;
      unsigned nxtv = (which == 0) ? s1 : (which == 1) ? s2 : (which == 2) ? s3 : s4;
      unsigned bsel = (unsigned)(4 * lane + (which < 0 ? 0 : which));
      bsel = __shfl(bsel, src, 64);
      nxtv = __shfl(nxtv, src, 64);
      prefix |= bsel << shift;
      pmask  |= 255u << shift;
      k_rem  -= nxtv;
    }
    unsigned tu = (prefix & 0x80000000u) ? (prefix ^ 0x80000000u) : ~prefix;
    thr = __uint_as_float(tu);
  }

  // ---- mask (stocks only) + running max ----
  float lmax = fmaxf(srow[0], srow[1]);   // anchors never masked
  for (int j = 0; j < 64; ++j) {
    int m = 2 + j * 64 + lane;
    float s = srow[m];
    if (s < thr) { s = -1e9f; srow[m] = s; }
    lmax = fmaxf(lmax, s);
  }
  #pragma unroll
  for (int off = 32; off > 0; off >>= 1) lmax = fmaxf(lmax, __shfl_xor(lmax, off, 64));

  // ---- exp + sum (store e in place) ----
  float lsumf = 0.f;
  for (int m = lane; m < M2; m += 64) {
    float e = __expf(srow[m] - lmax);
    srow[m] = e;
    lsumf += e;
  }
  #pragma unroll
  for (int off = 32; off > 0; off >>= 1) lsumf += __shfl_xor(lsumf, off, 64);
  float invZ = 1.0f / lsumf;
  if (lane == 0) invZ_all[h] = invZ;

  // ---- PV: out[d] = invZ * sum_m e[m] * v[m, h*64+d] ----
  {
    const int ph = lane >> 4;            // m phase 0..3
    const int dd = (lane & 15) << 2;     // d slice
    float ax = 0.f, ay = 0.f, az = 0.f, aw = 0.f;
    const float* vbh = vb + h * HD + dd;
    #pragma unroll 4
    for (int m0 = 0; m0 < M2; m0 += 4) {
      int mm = m0 + ph;
      float e = (mm < M2) ? srow[mm] : 0.f;
      float4 vv = *(const float4*)(vbh + (size_t)mm * DIM);
      ax += e * vv.x; ay += e * vv.y; az += e * vv.z; aw += e * vv.w;
    }
    ax += __shfl_xor(ax, 16, 64); ax += __shfl_xor(ax, 32, 64);
    ay += __shfl_xor(ay, 16, 64); ay += __shfl_xor(ay, 32, 64);
    az += __shfl_xor(az, 16, 64); az += __shfl_xor(az, 32, 64);
    aw += __shfl_xor(aw, 16, 64); aw += __shfl_xor(aw, 32, 64);
    if (lane < 16) {
      float4 o; o.x = ax * invZ; o.y = ay * invZ; o.z = az * invZ; o.w = aw * invZ;
      *(float4*)(attn_out + (size_t)n * DIM + h * HD + lane * 4) = o;
    }
  }
  __syncthreads();

  // ---- attn_mean = mean over heads of p = e * invZ ----
  for (int m = t; m < M2; m += 512) {
    float a = 0.f;
    #pragma unroll
    for (int hh = 0; hh < 8; ++hh) a += srow_all[hh * KTS + m] * invZ_all[hh];
    attn_mean_out[(size_t)n * M2 + m] = a * 0.125f;
  }
}

// ---------------- concat(stock_feats, proj) ----------------
__global__ __launch_bounds__(256) void cat_kernel(
    const float* __restrict__ sf, const float* __restrict__ pj, float* __restrict__ cat) {
  int idx = blockIdx.x * 256 + threadIdx.x;
  int n = idx >> 10, c = idx & 1023;
  cat[idx] = (c < 512) ? sf[(size_t)n * 512 + c] : pj[(size_t)n * 512 + (c - 512)];
}

// ---------------- gate, residual, RMSNorm, gate partial sums ----------------
__global__ __launch_bounds__(256) void final_kernel(
    const float* __restrict__ sf, const float* __restrict__ pj,
    const float* __restrict__ gl, const float* __restrict__ norm_w,
    float* __restrict__ outf, float* __restrict__ gpart) {
  int n = blockIdx.x, t = threadIdx.x;
  __shared__ float red[256];
  size_t base = (size_t)n * 512;
  float g0 = sigmoidf_(gl[base + t]);
  float g1 = sigmoidf_(gl[base + 256 + t]);
  float x0 = sf[base + t], x1 = sf[base + 256 + t];
  float p0 = pj[base + t], p1 = pj[base + 256 + t];
  float gr0 = x0 + g0 * p0, gr1 = x1 + g1 * p1;

  red[t] = g0 + g1;
  __syncthreads();
  for (int off = 128; off > 0; off >>= 1) {
    if (t < off) red[t] += red[t + off];
    __syncthreads();
  }
  if (t == 0) gpart[n] = red[0];
  __syncthreads();

  red[t] = gr0 * gr0 + gr1 * gr1;
  __syncthreads();
  for (int off = 128; off > 0; off >>= 1) {
    if (t < off) red[t] += red[t + off];
    __syncthreads();
  }
  float rms = rsqrtf(red[0] * (1.0f / 512.0f) + 1e-6f);
  outf[base + t] = gr0 * rms * norm_w[t];
  outf[base + 256 + t] = gr1 * rms * norm_w[256 + t];
}

__global__ __launch_bounds__(256) void gate_reduce(
    const float* __restrict__ gpart, float* __restrict__ out_scalar) {
  __shared__ float red[256];
  int t = threadIdx.x;
  float s = 0.f;
  for (int i = t; i < 4096; i += 256) s += gpart[i];
  red[t] = s;
  __syncthreads();
  for (int off = 128; off > 0; off >>= 1) {
    if (t < off) red[t] += red[t + off];
    __syncthreads();
  }
  if (t == 0) out_scalar[0] = red[0] * (1.0f / (4096.0f * 512.0f));
}

extern "C" void kernel_launch(void* const* d_in, const int* in_sizes, int n_in,
                              void* d_out, int out_size, void* d_ws, size_t ws_size,
                              hipStream_t stream) {
  const float* sf  = (const float*)d_in[0];
  const float* zp  = (const float*)d_in[1];
  const float* zs  = (const float*)d_in[2];
  const float* Wq  = (const float*)d_in[3];
  const float* Wk  = (const float*)d_in[4];
  const float* Wv  = (const float*)d_in[5];
  const float* Wg  = (const float*)d_in[6];
  const float* bg  = (const float*)d_in[7];
  const float* Wag = (const float*)d_in[8];
  const float* bag = (const float*)d_in[9];
  const float* nw  = (const float*)d_in[10];
  const float* Wo  = (const float*)d_in[11];
  const float* bo  = (const float*)d_in[12];

  float* out  = (float*)d_out;
  float* outF = out + OUT_F;
  float* outR = out + OUT_R;
  float* outG = out + OUT_G;
  float* outA = out + OUT_A;

  // workspace layout (floats)
  float* ws     = (float*)d_ws;
  float* regime = ws;                    // 512
  float* nodes  = ws + 512;              // 4098*512            -> 2,098,688
  float* qb     = ws + 2098688;          // 4096*512            -> 4,195,840
  float* Kt     = ws + 4195840;          // 512*4100 = 2,099,200-> 6,295,040
  float* vbuf   = ws + 6295040;          // 4098*512            -> 8,393,216
  float* ao     = ws + 8393216;          // 4096*512            -> 10,490,368
  float* pj     = ws + 10490368;         // 4096*512            -> 12,587,520
  float* gpart  = ws + 12587520;         // 4096                -> 12,591,616
  float* cat    = ws + 512;              // reuse nodes+qb region (4096*1024)
  float* gl     = ws + 4195840;          // reuse Kt region (4096*512)

  static int smem_set = 0;
  (void)smem_set;
  hipFuncSetAttribute((const void*)attn_kernel,
                      hipFuncAttributeMaxDynamicSharedMemorySize,
                      SMEM_FLOATS * 4);

  regime_kernel<<<1, 256, 0, stream>>>(zp, zs, Wg, bg, regime);
  build_nodes<<<8196, 256, 0, stream>>>(zp, zs, sf, nodes);
  gemm_bt<<<dim3(8, 64), 256, 0, stream>>>(sf,    Wq, nullptr, regime, qb,  4096, 512, 512, 512, 0);
  gemm_bt<<<dim3(8, 65), 256, 0, stream>>>(nodes, Wk, nullptr, nullptr, Kt,  4098, 512, 512, KTS, 1);
  gemm_bt<<<dim3(8, 65), 256, 0, stream>>>(nodes, Wv, nullptr, nullptr, vbuf,4098, 512, 512, 512, 0);
  attn_kernel<<<4096, 512, SMEM_FLOATS * 4, stream>>>(qb, Kt, vbuf, ao, outR, outA);
  gemm_bt<<<dim3(8, 64), 256, 0, stream>>>(ao, Wo, bo, nullptr, pj, 4096, 512, 512, 512, 0);
  cat_kernel<<<16384, 256, 0, stream>>>(sf, pj, cat);
  gemm_bt<<<dim3(8, 64), 256, 0, stream>>>(cat, Wag, bag, nullptr, gl, 4096, 512, 1024, 512, 0);
  final_kernel<<<4096, 256, 0, stream>>>(sf, pj, gl, nw, outF, gpart);
  gate_reduce<<<1, 256, 0, stream>>>(gpart, outG);
}

// Round 4
// 1713.734 us; speedup vs baseline: 21.4186x; 2.9329x over previous
//
#include <hip/hip_runtime.h>
#include <math.h>

// Problem constants
#define NS 4096      // N stocks
#define DIM 512      // D
#define NH 8         // heads
#define HD 64        // head dim
#define M2 4098      // N + 2 nodes
#define MPAD 4224    // m padded to 8*528
#define KKEEP 2048u  // top-k keep

// Output layout (floats): final_out | raw_scores | gate_mean | attn_mean
#define OUT_F 0
#define OUT_R 2097152          // 4096*512
#define OUT_G 18882560         // + 4096*4098
#define OUT_A 18882561

typedef __attribute__((ext_vector_type(8))) short bf16x8;
typedef __attribute__((ext_vector_type(4))) float f32x4;

__device__ __forceinline__ float sigmoidf_(float x) { return 1.0f / (1.0f + __expf(-x)); }

__device__ __forceinline__ unsigned short btrunc(float f) {   // f32 -> bf16 RNE
  unsigned u = __float_as_uint(f);
  u = u + 0x7FFFu + ((u >> 16) & 1u);
  return (unsigned short)(u >> 16);
}
__device__ __forceinline__ float bton(unsigned short h) {
  return __uint_as_float(((unsigned)h) << 16);
}

// ---------------- regime_mod = sigmoid([zp,zs] @ Wg.T + bg) ----------------
__global__ __launch_bounds__(256) void regime_kernel(
    const float* __restrict__ zp, const float* __restrict__ zs,
    const float* __restrict__ Wg, const float* __restrict__ bg,
    float* __restrict__ regime) {
  __shared__ float zc[1024];
  int t = threadIdx.x;
  for (int i = t; i < 512; i += 256) { zc[i] = zp[i]; zc[512 + i] = zs[i]; }
  __syncthreads();
  for (int j = t; j < 512; j += 256) {
    const float4* w = (const float4*)(Wg + (size_t)j * 1024);
    float acc = 0.f;
    #pragma unroll 8
    for (int i = 0; i < 256; i++) {
      float4 wv = w[i];
      acc += wv.x * zc[4*i] + wv.y * zc[4*i+1] + wv.z * zc[4*i+2] + wv.w * zc[4*i+3];
    }
    regime[j] = sigmoidf_(acc + bg[j]);
  }
}

// ---------------- generic f32 -> bf16 convert ----------------
__global__ __launch_bounds__(256) void conv_bf(
    const float* __restrict__ src, unsigned short* __restrict__ dst, int n4) {
  int i4 = blockIdx.x * 256 + threadIdx.x;
  if (i4 >= n4) return;
  float4 v = *(const float4*)(src + (size_t)i4 * 4);
  ushort4 o; o.x = btrunc(v.x); o.y = btrunc(v.y); o.z = btrunc(v.z); o.w = btrunc(v.w);
  *(ushort4*)(dst + (size_t)i4 * 4) = o;
}

// ---------------- nodes = concat(zp, zs, sf) in bf16 ----------------
__global__ __launch_bounds__(256) void build_nodes_bf(
    const float* __restrict__ zp, const float* __restrict__ zs,
    const float* __restrict__ sf, unsigned short* __restrict__ nb) {
  int i4 = blockIdx.x * 256 + threadIdx.x;
  if (i4 >= (M2 * DIM) / 4) return;
  int idx = i4 * 4;
  int m = idx >> 9, c = idx & 511;
  const float* src = (m == 0) ? (zp + c) : (m == 1) ? (zs + c)
                               : (sf + (size_t)(m - 2) * 512 + c);
  float4 v = *(const float4*)src;
  ushort4 o; o.x = btrunc(v.x); o.y = btrunc(v.y); o.z = btrunc(v.z); o.w = btrunc(v.w);
  *(ushort4*)(nb + idx) = o;
}

// ---------------- bf16 MFMA GEMM: C = (A[M][K] @ B[N][K]^T * scale + bias) * cscale ----------------
// 128x128 tile, 256 threads (4 waves in 2x2), BK=32.
// mode 0: C fp32 [M][ldc]; mode 1: C bf16 [M][ldc]; mode 2: C bf16 transposed [N][ldc] (C[col][row]).
#define LSTR 40
__global__ __launch_bounds__(256) void gemm_bf16(
    const unsigned short* __restrict__ A, const unsigned short* __restrict__ B,
    const float* __restrict__ bias, const float* __restrict__ cscale,
    float* __restrict__ Cf, unsigned short* __restrict__ Cb,
    int M, int N, int K, int lda, int ldb, int ldc, float scale, int mode) {
  __shared__ unsigned short As[128 * LSTR];
  __shared__ unsigned short Bs[128 * LSTR];
  const int t = threadIdx.x;
  const int w = t >> 6, lane = t & 63;
  const int wr = w >> 1, wc = w & 1;
  const int lr = lane & 15, lg = lane >> 4;
  const int bm = blockIdx.y * 128, bn = blockIdx.x * 128;
  f32x4 acc[4][4] = {};
  for (int k0 = 0; k0 < K; k0 += 32) {
    #pragma unroll
    for (int i = 0; i < 2; i++) {
      int q = t + i * 256;
      int row = q >> 2;
      int ko = (q & 3) * 8;
      bf16x8 av = {};
      int gr = bm + row;
      if (gr < M) av = *(const bf16x8*)(A + (size_t)gr * lda + k0 + ko);
      *(bf16x8*)(As + row * LSTR + ko) = av;
      bf16x8 bv = {};
      int gbr = bn + row;
      if (gbr < N) bv = *(const bf16x8*)(B + (size_t)gbr * ldb + k0 + ko);
      *(bf16x8*)(Bs + row * LSTR + ko) = bv;
    }
    __syncthreads();
    {
      bf16x8 af[4], bfr[4];
      #pragma unroll
      for (int i = 0; i < 4; i++)
        af[i] = *(const bf16x8*)(As + (64 * wr + 16 * i + lr) * LSTR + lg * 8);
      #pragma unroll
      for (int j = 0; j < 4; j++)
        bfr[j] = *(const bf16x8*)(Bs + (64 * wc + 16 * j + lr) * LSTR + lg * 8);
      #pragma unroll
      for (int i = 0; i < 4; i++)
        #pragma unroll
        for (int j = 0; j < 4; j++)
          acc[i][j] = __builtin_amdgcn_mfma_f32_16x16x32_bf16(af[i], bfr[j], acc[i][j], 0, 0, 0);
    }
    __syncthreads();
  }
  // epilogue
  #pragma unroll
  for (int i = 0; i < 4; i++) {
    #pragma unroll
    for (int j = 0; j < 4; j++) {
      #pragma unroll
      for (int q = 0; q < 4; q++) {
        int row = bm + 64 * wr + 16 * i + lg * 4 + q;
        int col = bn + 64 * wc + 16 * j + lr;
        if (row < M && col < N) {
          float v = acc[i][j][q] * scale;
          if (bias)   v += bias[col];
          if (cscale) v *= cscale[col];
          if (mode == 0)      Cf[(size_t)row * ldc + col] = v;
          else if (mode == 1) Cb[(size_t)row * ldc + col] = btrunc(v);
          else                Cb[(size_t)col * ldc + row] = btrunc(v);
        }
      }
    }
  }
}

// ---------------- fused attention ----------------
// One block per 16-row tile (256 blocks, 1/CU), 512 threads = 8 waves, loop h=0..7.
// Per head: QK^T MFMA -> S (bf16, swizzled LDS) -> per-wave exact bf16 rank-2048
// radix select -> softmax (NORMALIZED P stored back) -> attn_mean accumulated in
// VGPRs (no atomics) -> PV MFMA (K-split over 8 waves) -> LDS reduce -> aobf.
#define SROWB (MPAD * 2)              // 8448 bytes per LDS S row
#define QOFF  (16 * SROWB)            // 135168
#define HOFF  (QOFF + 16 * 72 * 2)    // + 2304 = 137472
#define SMEMSZ (HOFF + 8 * 256 * 4)   // + 8192 = 145664

__global__ __launch_bounds__(512, 2) void fused_attn(
    const unsigned short* __restrict__ Qbf, const unsigned short* __restrict__ Kbf,
    const unsigned short* __restrict__ Vt, unsigned short* __restrict__ aobf,
    float* __restrict__ attn_mean_out) {
  extern __shared__ char dsm[];
  unsigned short* qt = (unsigned short*)(dsm + QOFF);
  unsigned* hist = (unsigned*)(dsm + HOFF);

  const int n0 = blockIdx.x * 16;
  const int t = threadIdx.x;
  const int w = t >> 6, lane = t & 63;
  const int lr = lane & 15, lg = lane >> 4;
  const int arow = t >> 5, ac = t & 31;
  unsigned* hw = hist + w * 256;

  float am[129];
  #pragma unroll
  for (int j = 0; j < 129; ++j) am[j] = 0.f;

  for (int h = 0; h < NH; ++h) {
    // ---- ph0: Q tile -> LDS (16 x 64, stride 72) ----
    for (int i = t; i < 1024; i += 512)
      qt[(i >> 6) * 72 + (i & 63)] = Qbf[(size_t)(n0 + (i >> 6)) * DIM + h * HD + (i & 63)];
    __syncthreads();

    // ---- ph1: S = Q @ K^T * 0.125 -> LDS bf16 (swizzled) ----
    {
      bf16x8 a0 = *(const bf16x8*)(qt + lr * 72 + lg * 8);
      bf16x8 a1 = *(const bf16x8*)(qt + lr * 72 + 32 + lg * 8);
      for (int f = 0; f < 33; ++f) {
        int m0 = w * 528 + f * 16;
        const unsigned short* kp = Kbf + (size_t)(m0 + lr) * DIM + h * HD + lg * 8;
        bf16x8 b0 = *(const bf16x8*)(kp);
        bf16x8 b1 = *(const bf16x8*)(kp + 32);
        f32x4 c = {0.f, 0.f, 0.f, 0.f};
        c = __builtin_amdgcn_mfma_f32_16x16x32_bf16(a0, b0, c, 0, 0, 0);
        c = __builtin_amdgcn_mfma_f32_16x16x32_bf16(a1, b1, c, 0, 0, 0);
        int m = m0 + lr;
        #pragma unroll
        for (int q = 0; q < 4; ++q) {
          int r = lg * 4 + q;
          *(unsigned short*)(dsm + r * SROWB + ((2 * m) ^ ((r & 7) << 4))) = btrunc(c[q] * 0.125f);
        }
      }
    }
    __syncthreads();

    // ---- ph2: per-wave rows 2w, 2w+1: select + softmax, store NORMALIZED P ----
    for (int rr = 0; rr < 2; ++rr) {
      const int r = 2 * w + rr;
      unsigned thrkey = 0;
      {
        unsigned k_rem = KKEEP, tb = 0;
        for (int pass = 0; pass < 2; ++pass) {
          hw[lane] = 0u; hw[lane + 64] = 0u; hw[lane + 128] = 0u; hw[lane + 192] = 0u;
          for (int j = 0; j < 64; ++j) {
            int m = 2 + j * 64 + lane;
            unsigned short us = *(const unsigned short*)(dsm + r * SROWB + ((2 * m) ^ ((r & 7) << 4)));
            unsigned key = ((unsigned)us ^ ((us >> 15) ? 0xFFFFu : 0x8000u)) & 0xFFFFu;
            unsigned bin; bool active;
            if (pass == 0) { bin = key >> 8; active = true; }
            else           { bin = key & 255u; active = ((key >> 8) == tb); }
            if (active) atomicAdd(&hw[bin], 1u);
          }
          unsigned c0 = hw[4*lane], c1 = hw[4*lane+1], c2 = hw[4*lane+2], c3 = hw[4*lane+3];
          unsigned run = c0 + c1 + c2 + c3;
          #pragma unroll
          for (int off = 1; off < 64; off <<= 1) {
            unsigned o_ = __shfl_down(run, off, 64);
            if (lane + off < 64) run += o_;
          }
          unsigned s0 = run, s1 = run - c0, s2 = s1 - c1, s3 = s2 - c2, s4 = s3 - c3;
          int which = -1;
          if      (s0 >= k_rem && s1 < k_rem) which = 0;
          else if (s1 >= k_rem && s2 < k_rem) which = 1;
          else if (s2 >= k_rem && s3 < k_rem) which = 2;
          else if (s3 >= k_rem && s4 < k_rem) which = 3;
          unsigned long long bal = __ballot(which >= 0);
          int src = (int)__ffsll(bal) - 1;
          unsigned nxtv = (which == 0) ? s1 : (which == 1) ? s2 : (which == 2) ? s3 : s4;
          unsigned bsel = (unsigned)(4 * lane + (which < 0 ? 0 : which));
          bsel = (unsigned)__shfl((int)bsel, src, 64);
          nxtv = (unsigned)__shfl((int)nxtv, src, 64);
          if (pass == 0) tb = bsel; else thrkey = (tb << 8) | bsel;
          k_rem -= nxtv;
        }
      }
      // max over kept (+ anchors)
      float lmax = -3.0e38f;
      for (int j = 0; j <= 64; ++j) {
        int m = lane + 64 * j;
        if (m < M2) {
          unsigned short us = *(const unsigned short*)(dsm + r * SROWB + ((2 * m) ^ ((r & 7) << 4)));
          unsigned key = ((unsigned)us ^ ((us >> 15) ? 0xFFFFu : 0x8000u)) & 0xFFFFu;
          bool kept = (m < 2) || (key >= thrkey);
          if (kept) lmax = fmaxf(lmax, bton(us));
        }
      }
      #pragma unroll
      for (int off = 32; off > 0; off >>= 1) lmax = fmaxf(lmax, __shfl_xor(lmax, off, 64));
      // exp + sum (store e bf16 in place)
      float lsum = 0.f;
      for (int j = 0; j <= 64; ++j) {
        int m = lane + 64 * j;
        if (m < M2) {
          char* ap = dsm + r * SROWB + ((2 * m) ^ ((r & 7) << 4));
          unsigned short us = *(const unsigned short*)ap;
          unsigned key = ((unsigned)us ^ ((us >> 15) ? 0xFFFFu : 0x8000u)) & 0xFFFFu;
          bool kept = (m < 2) || (key >= thrkey);
          float e = kept ? __expf(bton(us) - lmax) : 0.f;
          unsigned short eb = btrunc(e);
          *(unsigned short*)ap = eb;
          lsum += bton(eb);
        }
      }
      for (int m = M2 + lane; m < MPAD; m += 64)
        *(unsigned short*)(dsm + r * SROWB + ((2 * m) ^ ((r & 7) << 4))) = 0;
      #pragma unroll
      for (int off = 32; off > 0; off >>= 1) lsum += __shfl_xor(lsum, off, 64);
      float invZ = 1.0f / lsum;
      // normalize in place: P = e * invZ  (bf16)
      for (int j = 0; j <= 64; ++j) {
        int m = lane + 64 * j;
        if (m < M2) {
          char* ap = dsm + r * SROWB + ((2 * m) ^ ((r & 7) << 4));
          *(unsigned short*)ap = btrunc(bton(*(unsigned short*)ap) * invZ);
        }
      }
    }
    __syncthreads();

    // ---- ph2.5: attn_mean accumulation in VGPRs (thread: row=t>>5, m = (t&31)+32j) ----
    #pragma unroll
    for (int j = 0; j < 129; ++j) {
      if (j < 128 || ac < 2) {
        int m = ac + 32 * j;
        am[j] += bton(*(const unsigned short*)(dsm + arow * SROWB + ((2 * m) ^ ((arow & 7) << 4))));
      }
    }

    // ---- ph3: PV = P @ V (K-split over waves); P already normalized ----
    {
      const int nks = (w < 4) ? 17 : 16;
      const int ks0 = w * 16 + ((w < 4) ? w : 4);
      f32x4 o0 = {0.f,0.f,0.f,0.f}, o1 = o0, o2 = o0, o3 = o0;
      const unsigned short* Vb = Vt + (size_t)(h * HD) * MPAD;
      for (int ks = 0; ks < nks; ks++) {
        int kk = (ks0 + ks) * 32 + lg * 8;
        bf16x8 a = *(const bf16x8*)(dsm + lr * SROWB + ((2 * kk) ^ ((lr & 7) << 4)));
        bf16x8 b0 = *(const bf16x8*)(Vb + (size_t)(lr) * MPAD + kk);
        bf16x8 b1 = *(const bf16x8*)(Vb + (size_t)(16 + lr) * MPAD + kk);
        bf16x8 b2 = *(const bf16x8*)(Vb + (size_t)(32 + lr) * MPAD + kk);
        bf16x8 b3 = *(const bf16x8*)(Vb + (size_t)(48 + lr) * MPAD + kk);
        o0 = __builtin_amdgcn_mfma_f32_16x16x32_bf16(a, b0, o0, 0, 0, 0);
        o1 = __builtin_amdgcn_mfma_f32_16x16x32_bf16(a, b1, o1, 0, 0, 0);
        o2 = __builtin_amdgcn_mfma_f32_16x16x32_bf16(a, b2, o2, 0, 0, 0);
        o3 = __builtin_amdgcn_mfma_f32_16x16x32_bf16(a, b3, o3, 0, 0, 0);
      }
      __syncthreads();   // all waves done reading P (and ph2.5 reads)
      float* part = (float*)dsm;   // [8][16][64] overlaps S rows 0..3
      #pragma unroll
      for (int q = 0; q < 4; q++) {
        int row = lg * 4 + q;
        part[w * 1024 + row * 64 +      lr] = o0[q];
        part[w * 1024 + row * 64 + 16 + lr] = o1[q];
        part[w * 1024 + row * 64 + 32 + lr] = o2[q];
        part[w * 1024 + row * 64 + 48 + lr] = o3[q];
      }
      __syncthreads();
      for (int i = t; i < 1024; i += 512) {
        float s = 0.f;
        #pragma unroll
        for (int ww = 0; ww < 8; ww++) s += part[ww * 1024 + i];
        int r = i >> 6, d = i & 63;
        aobf[(size_t)(n0 + r) * DIM + h * HD + d] = btrunc(s);
      }
      __syncthreads();   // before next h overwrites S / qt
    }
  }

  // ---- write attn_mean (exactly once, no atomics) ----
  #pragma unroll
  for (int j = 0; j < 129; ++j)
    if (j < 128 || ac < 2)
      attn_mean_out[(size_t)(n0 + arow) * M2 + ac + 32 * j] = am[j] * 0.125f;
}

// ---------------- concat(sfbf, bf16(pj)) ----------------
__global__ __launch_bounds__(256) void cat_bf(
    const unsigned short* __restrict__ sfbf, const float* __restrict__ pj,
    unsigned short* __restrict__ cat) {
  int i4 = blockIdx.x * 256 + threadIdx.x;
  if (i4 >= (4096 * 1024) / 4) return;
  int idx = i4 * 4;
  int n = idx >> 10, c = idx & 1023;
  if (c < 512) {
    *(ushort4*)(cat + idx) = *(const ushort4*)(sfbf + (size_t)n * 512 + c);
  } else {
    float4 v = *(const float4*)(pj + (size_t)n * 512 + (c - 512));
    ushort4 o; o.x = btrunc(v.x); o.y = btrunc(v.y); o.z = btrunc(v.z); o.w = btrunc(v.w);
    *(ushort4*)(cat + idx) = o;
  }
}

// ---------------- gate, residual, RMSNorm, gate partial sums ----------------
__global__ __launch_bounds__(256) void final_kernel(
    const float* __restrict__ sf, const float* __restrict__ pj,
    const float* __restrict__ gl, const float* __restrict__ norm_w,
    float* __restrict__ outf, float* __restrict__ gpart) {
  int n = blockIdx.x, t = threadIdx.x;
  __shared__ float red[256];
  size_t base = (size_t)n * 512;
  float g0 = sigmoidf_(gl[base + t]);
  float g1 = sigmoidf_(gl[base + 256 + t]);
  float x0 = sf[base + t], x1 = sf[base + 256 + t];
  float p0 = pj[base + t], p1 = pj[base + 256 + t];
  float gr0 = x0 + g0 * p0, gr1 = x1 + g1 * p1;

  red[t] = g0 + g1;
  __syncthreads();
  for (int off = 128; off > 0; off >>= 1) {
    if (t < off) red[t] += red[t + off];
    __syncthreads();
  }
  if (t == 0) gpart[n] = red[0];
  __syncthreads();

  red[t] = gr0 * gr0 + gr1 * gr1;
  __syncthreads();
  for (int off = 128; off > 0; off >>= 1) {
    if (t < off) red[t] += red[t + off];
    __syncthreads();
  }
  float rms = rsqrtf(red[0] * (1.0f / 512.0f) + 1e-6f);
  outf[base + t] = gr0 * rms * norm_w[t];
  outf[base + 256 + t] = gr1 * rms * norm_w[256 + t];
}

__global__ __launch_bounds__(256) void gate_reduce(
    const float* __restrict__ gpart, float* __restrict__ out_scalar) {
  __shared__ float red[256];
  int t = threadIdx.x;
  float s = 0.f;
  for (int i = t; i < 4096; i += 256) s += gpart[i];
  red[t] = s;
  __syncthreads();
  for (int off = 128; off > 0; off >>= 1) {
    if (t < off) red[t] += red[t + off];
    __syncthreads();
  }
  if (t == 0) out_scalar[0] = red[0] * (1.0f / (4096.0f * 512.0f));
}

extern "C" void kernel_launch(void* const* d_in, const int* in_sizes, int n_in,
                              void* d_out, int out_size, void* d_ws, size_t ws_size,
                              hipStream_t stream) {
  const float* sf  = (const float*)d_in[0];
  const float* zp  = (const float*)d_in[1];
  const float* zs  = (const float*)d_in[2];
  const float* Wq  = (const float*)d_in[3];
  const float* Wk  = (const float*)d_in[4];
  const float* Wv  = (const float*)d_in[5];
  const float* Wg  = (const float*)d_in[6];
  const float* bg  = (const float*)d_in[7];
  const float* Wag = (const float*)d_in[8];
  const float* bag = (const float*)d_in[9];
  const float* nw  = (const float*)d_in[10];
  const float* Wo  = (const float*)d_in[11];
  const float* bo  = (const float*)d_in[12];

  float* out  = (float*)d_out;
  float* outF = out + OUT_F;
  float* outR = out + OUT_R;
  float* outG = out + OUT_G;
  float* outA = out + OUT_A;

  // workspace layout (bytes)
  char* W = (char*)d_ws;
  float*          regime  = (float*)(W + 0);                 // 2048
  float*          gpart   = (float*)(W + 2048);              // 16384
  unsigned short* sfbf    = (unsigned short*)(W + 18432);    // 4,194,304
  unsigned short* nodesbf = (unsigned short*)(W + 4212736);  // 4,196,352
  unsigned short* Qbf     = (unsigned short*)(W + 8409088);  // 4,194,304
  unsigned short* Kbf     = (unsigned short*)(W + 12603392); // 4,325,376 (4224 rows)
  unsigned short* Vt      = (unsigned short*)(W + 16928768); // 4,325,376 (512 x 4224)
  unsigned short* aobf    = (unsigned short*)(W + 21254144); // 4,194,304
  unsigned short* catbf   = (unsigned short*)(W + 25448448); // 8,388,608
  unsigned short* Wqbf    = (unsigned short*)(W + 33837056); // 524,288
  unsigned short* Wkbf    = (unsigned short*)(W + 34361344); // 524,288
  unsigned short* Wvbf    = (unsigned short*)(W + 34885632); // 524,288
  unsigned short* Wobf    = (unsigned short*)(W + 35409920); // 524,288
  unsigned short* Wagbf   = (unsigned short*)(W + 35934208); // 1,048,576
  float*          pj      = (float*)(W + 36982784);          // 8,388,608 -> 45,371,392
  float*          gl      = (float*)(W + 4212736);           // alias over nodesbf+Qbf (dead by then)

  hipFuncSetAttribute((const void*)fused_attn,
                      hipFuncAttributeMaxDynamicSharedMemorySize, SMEMSZ);

  // --- small prep ---
  regime_kernel<<<1, 256, 0, stream>>>(zp, zs, Wg, bg, regime);
  conv_bf<<<2048, 256, 0, stream>>>(sf, sfbf, 524288);
  build_nodes_bf<<<2049, 256, 0, stream>>>(zp, zs, sf, nodesbf);
  conv_bf<<<256, 256, 0, stream>>>(Wq, Wqbf, 65536);
  conv_bf<<<256, 256, 0, stream>>>(Wk, Wkbf, 65536);
  conv_bf<<<256, 256, 0, stream>>>(Wv, Wvbf, 65536);
  conv_bf<<<256, 256, 0, stream>>>(Wo, Wobf, 65536);
  conv_bf<<<512, 256, 0, stream>>>(Wag, Wagbf, 131072);
  hipMemsetAsync(Kbf, 0, 4325376, stream);
  hipMemsetAsync(Vt, 0, 4325376, stream);

  // --- projections (bf16 MFMA) ---
  gemm_bf16<<<dim3(4, 32), 256, 0, stream>>>(sfbf, Wqbf, nullptr, regime, nullptr, Qbf,
                                             4096, 512, 512, 512, 512, 512, 1.0f, 1);
  gemm_bf16<<<dim3(4, 33), 256, 0, stream>>>(nodesbf, Wkbf, nullptr, nullptr, nullptr, Kbf,
                                             M2, 512, 512, 512, 512, 512, 1.0f, 1);
  gemm_bf16<<<dim3(4, 33), 256, 0, stream>>>(nodesbf, Wvbf, nullptr, nullptr, nullptr, Vt,
                                             M2, 512, 512, 512, 512, MPAD, 1.0f, 2);

  // --- raw_scores = (Q @ K^T) * (0.125/8) over full 512 dims ---
  gemm_bf16<<<dim3(33, 32), 256, 0, stream>>>(Qbf, Kbf, nullptr, nullptr, outR, nullptr,
                                              4096, M2, 512, 512, 512, M2, 0.015625f, 0);

  // --- fused attention (256 blocks, no atomics) ---
  fused_attn<<<256, 512, SMEMSZ, stream>>>(Qbf, Kbf, Vt, aobf, outA);

  // --- output projection + gate + final ---
  gemm_bf16<<<dim3(4, 32), 256, 0, stream>>>(aobf, Wobf, bo, nullptr, pj, nullptr,
                                             4096, 512, 512, 512, 512, 512, 1.0f, 0);
  cat_bf<<<4096, 256, 0, stream>>>(sfbf, pj, catbf);
  gemm_bf16<<<dim3(4, 32), 256, 0, stream>>>(catbf, Wagbf, bag, nullptr, gl, nullptr,
                                             4096, 512, 1024, 1024, 1024, 512, 1.0f, 0);
  final_kernel<<<4096, 256, 0, stream>>>(sf, pj, gl, nw, outF, gpart);
  gate_reduce<<<1, 256, 0, stream>>>(gpart, outG);
}

// Round 5
// 1126.661 us; speedup vs baseline: 32.5793x; 1.5211x over previous
//
#include <hip/hip_runtime.h>
#include <math.h>

// Problem constants
#define NS 4096      // N stocks
#define DIM 512      // D
#define NH 8         // heads
#define HD 64        // head dim
#define M2 4098      // N + 2 nodes
#define MPAD 4224    // m padded to multiple of 32 (132 k-slices of 32)
#define KKEEP 2048u  // top-k keep

// Output layout (floats): final_out | raw_scores | gate_mean | attn_mean
#define OUT_F 0
#define OUT_R 2097152          // 4096*512
#define OUT_G 18882560         // + 4096*4098
#define OUT_A 18882561

typedef __attribute__((ext_vector_type(8))) short bf16x8;
typedef __attribute__((ext_vector_type(4))) float f32x4;

__device__ __forceinline__ float sigmoidf_(float x) { return 1.0f / (1.0f + __expf(-x)); }

__device__ __forceinline__ unsigned short btrunc(float f) {   // f32 -> bf16 RNE
  unsigned u = __float_as_uint(f);
  u = u + 0x7FFFu + ((u >> 16) & 1u);
  return (unsigned short)(u >> 16);
}
__device__ __forceinline__ float bton(unsigned short h) {
  return __uint_as_float(((unsigned)h) << 16);
}

// ---------------- regime_mod = sigmoid([zp,zs] @ Wg.T + bg) ----------------
__global__ __launch_bounds__(256) void regime_kernel(
    const float* __restrict__ zp, const float* __restrict__ zs,
    const float* __restrict__ Wg, const float* __restrict__ bg,
    float* __restrict__ regime) {
  __shared__ float zc[1024];
  int t = threadIdx.x;
  for (int i = t; i < 512; i += 256) { zc[i] = zp[i]; zc[512 + i] = zs[i]; }
  __syncthreads();
  for (int j = t; j < 512; j += 256) {
    const float4* w = (const float4*)(Wg + (size_t)j * 1024);
    float acc = 0.f;
    #pragma unroll 8
    for (int i = 0; i < 256; i++) {
      float4 wv = w[i];
      acc += wv.x * zc[4*i] + wv.y * zc[4*i+1] + wv.z * zc[4*i+2] + wv.w * zc[4*i+3];
    }
    regime[j] = sigmoidf_(acc + bg[j]);
  }
}

// ---------------- generic f32 -> bf16 convert ----------------
__global__ __launch_bounds__(256) void conv_bf(
    const float* __restrict__ src, unsigned short* __restrict__ dst, int n4) {
  int i4 = blockIdx.x * 256 + threadIdx.x;
  if (i4 >= n4) return;
  float4 v = *(const float4*)(src + (size_t)i4 * 4);
  ushort4 o; o.x = btrunc(v.x); o.y = btrunc(v.y); o.z = btrunc(v.z); o.w = btrunc(v.w);
  *(ushort4*)(dst + (size_t)i4 * 4) = o;
}

// ---------------- nodes = concat(zp, zs, sf) in bf16 ----------------
__global__ __launch_bounds__(256) void build_nodes_bf(
    const float* __restrict__ zp, const float* __restrict__ zs,
    const float* __restrict__ sf, unsigned short* __restrict__ nb) {
  int i4 = blockIdx.x * 256 + threadIdx.x;
  if (i4 >= (M2 * DIM) / 4) return;
  int idx = i4 * 4;
  int m = idx >> 9, c = idx & 511;
  const float* src = (m == 0) ? (zp + c) : (m == 1) ? (zs + c)
                               : (sf + (size_t)(m - 2) * 512 + c);
  float4 v = *(const float4*)src;
  ushort4 o; o.x = btrunc(v.x); o.y = btrunc(v.y); o.z = btrunc(v.z); o.w = btrunc(v.w);
  *(ushort4*)(nb + idx) = o;
}

// ---------------- bf16 MFMA GEMM: C = (A[M][K] @ B[N][K]^T * scale + bias) * cscale ----------------
// 128x128 tile, 256 threads (4 waves in 2x2), BK=32.
// mode 0: C fp32 [M][ldc]; mode 1: C bf16 [M][ldc]; mode 2: C bf16 transposed [N][ldc] (C[col][row]).
#define LSTR 40
__global__ __launch_bounds__(256) void gemm_bf16(
    const unsigned short* __restrict__ A, const unsigned short* __restrict__ B,
    const float* __restrict__ bias, const float* __restrict__ cscale,
    float* __restrict__ Cf, unsigned short* __restrict__ Cb,
    int M, int N, int K, int lda, int ldb, int ldc, float scale, int mode) {
  __shared__ unsigned short As[128 * LSTR];
  __shared__ unsigned short Bs[128 * LSTR];
  const int t = threadIdx.x;
  const int w = t >> 6, lane = t & 63;
  const int wr = w >> 1, wc = w & 1;
  const int lr = lane & 15, lg = lane >> 4;
  const int bm = blockIdx.y * 128, bn = blockIdx.x * 128;
  f32x4 acc[4][4] = {};
  for (int k0 = 0; k0 < K; k0 += 32) {
    #pragma unroll
    for (int i = 0; i < 2; i++) {
      int q = t + i * 256;
      int row = q >> 2;
      int ko = (q & 3) * 8;
      bf16x8 av = {};
      int gr = bm + row;
      if (gr < M) av = *(const bf16x8*)(A + (size_t)gr * lda + k0 + ko);
      *(bf16x8*)(As + row * LSTR + ko) = av;
      bf16x8 bv = {};
      int gbr = bn + row;
      if (gbr < N) bv = *(const bf16x8*)(B + (size_t)gbr * ldb + k0 + ko);
      *(bf16x8*)(Bs + row * LSTR + ko) = bv;
    }
    __syncthreads();
    {
      bf16x8 af[4], bfr[4];
      #pragma unroll
      for (int i = 0; i < 4; i++)
        af[i] = *(const bf16x8*)(As + (64 * wr + 16 * i + lr) * LSTR + lg * 8);
      #pragma unroll
      for (int j = 0; j < 4; j++)
        bfr[j] = *(const bf16x8*)(Bs + (64 * wc + 16 * j + lr) * LSTR + lg * 8);
      #pragma unroll
      for (int i = 0; i < 4; i++)
        #pragma unroll
        for (int j = 0; j < 4; j++)
          acc[i][j] = __builtin_amdgcn_mfma_f32_16x16x32_bf16(af[i], bfr[j], acc[i][j], 0, 0, 0);
    }
    __syncthreads();
  }
  // epilogue
  #pragma unroll
  for (int i = 0; i < 4; i++) {
    #pragma unroll
    for (int j = 0; j < 4; j++) {
      #pragma unroll
      for (int q = 0; q < 4; q++) {
        int row = bm + 64 * wr + 16 * i + lg * 4 + q;
        int col = bn + 64 * wc + 16 * j + lr;
        if (row < M && col < N) {
          float v = acc[i][j][q] * scale;
          if (bias)   v += bias[col];
          if (cscale) v *= cscale[col];
          if (mode == 0)      Cf[(size_t)row * ldc + col] = v;
          else if (mode == 1) Cb[(size_t)row * ldc + col] = btrunc(v);
          else                Cb[(size_t)col * ldc + row] = btrunc(v);
        }
      }
    }
  }
}

// ---------------- fused attention ----------------
// 256 blocks (one 16-row tile each, 1/CU), 1024 threads = 16 waves, loop h=0..7.
// Per head: QK^T MFMA (16-way col split) -> S bf16 swizzled LDS ->
// per-wave (1 row each) REGISTER-RESIDENT exact bf16 rank-2048 radix select +
// softmax (P normalized, written back b128) -> attn_mean coalesced global RMW ->
// PV MFMA (16-way K-split) -> LDS reduce -> aobf.
#define SROWB (MPAD * 2)              // 8448 bytes per LDS S row
#define QOFF  (16 * SROWB)            // 135168
#define HOFF  (QOFF + 16 * 72 * 2)    // + 2304 = 137472
#define SMEMSZ (HOFF + 16 * 256 * 4)  // + 16384 = 153856

__global__ __launch_bounds__(1024, 4) void fused_attn(
    const unsigned short* __restrict__ Qbf, const unsigned short* __restrict__ Kbf,
    const unsigned short* __restrict__ Vt, unsigned short* __restrict__ aobf,
    float* __restrict__ attn_mean_out) {
  extern __shared__ char dsm[];
  unsigned short* qt = (unsigned short*)(dsm + QOFF);
  unsigned* hist = (unsigned*)(dsm + HOFF);

  const int n0 = blockIdx.x * 16;
  const int t = threadIdx.x;
  const int w = t >> 6, lane = t & 63;
  const int lr = lane & 15, lg = lane >> 4;
  unsigned* hw = hist + w * 256;
  const int r = w;                              // ph2 row owned by this wave
  const unsigned swz = (unsigned)((r & 7) << 4);

  for (int h = 0; h < NH; ++h) {
    // ---- ph0: Q tile -> LDS (16 x 64, stride 72); one elem per thread ----
    qt[(t >> 6) * 72 + (t & 63)] = Qbf[(size_t)(n0 + (t >> 6)) * DIM + h * HD + (t & 63)];
    __syncthreads();

    // ---- ph1: S = Q @ K^T * 0.125 -> LDS bf16 (swizzled) ----
    {
      bf16x8 a0 = *(const bf16x8*)(qt + lr * 72 + lg * 8);
      bf16x8 a1 = *(const bf16x8*)(qt + lr * 72 + 32 + lg * 8);
      const int cw = (w < 8) ? 17 : 16;
      const int sw = (w < 8) ? w * 17 : 136 + (w - 8) * 16;
      for (int f = 0; f < cw; ++f) {
        int m0 = (sw + f) * 16;
        const unsigned short* kp = Kbf + (size_t)(m0 + lr) * DIM + h * HD + lg * 8;
        bf16x8 b0 = *(const bf16x8*)(kp);
        bf16x8 b1 = *(const bf16x8*)(kp + 32);
        f32x4 c = {0.f, 0.f, 0.f, 0.f};
        c = __builtin_amdgcn_mfma_f32_16x16x32_bf16(a0, b0, c, 0, 0, 0);
        c = __builtin_amdgcn_mfma_f32_16x16x32_bf16(a1, b1, c, 0, 0, 0);
        int m = m0 + lr;
        #pragma unroll
        for (int q = 0; q < 4; ++q) {
          int rr = lg * 4 + q;
          *(unsigned short*)(dsm + rr * SROWB + ((2 * m) ^ ((rr & 7) << 4))) = btrunc(c[q] * 0.125f);
        }
      }
    }
    __syncthreads();

    // ---- ph2: register-resident select + softmax for row r = w ----
    {
      // load full S row into registers (9 x b128)
      uint4 rv[9];
      #pragma unroll
      for (int c = 0; c < 8; ++c)
        rv[c] = *(const uint4*)(dsm + r * SROWB + (((unsigned)(c * 1024 + lane * 16)) ^ swz));
      rv[8] = make_uint4(0u, 0u, 0u, 0u);
      if (lane < 16)
        rv[8] = *(const uint4*)(dsm + r * SROWB + (((unsigned)(8192 + lane * 16)) ^ swz));

      // exact rank-2048 radix select on 16-bit monotone keys
      unsigned thrkey = 0;
      {
        unsigned k_rem = KKEEP, tb = 0;
        for (int pass = 0; pass < 2; ++pass) {
          hw[lane] = 0u; hw[lane + 64] = 0u; hw[lane + 128] = 0u; hw[lane + 192] = 0u;
          #pragma unroll
          for (int c = 0; c < 9; ++c) {
            const unsigned* pw = (const unsigned*)&rv[c];
            #pragma unroll
            for (int p2 = 0; p2 < 4; ++p2) {
              unsigned pk = pw[p2];
              int mb = c * 512 + lane * 8 + p2 * 2;
              #pragma unroll
              for (int e = 0; e < 2; ++e) {
                int m = mb + e;
                unsigned u = (e == 0) ? (pk & 0xFFFFu) : (pk >> 16);
                unsigned key = u ^ ((u & 0x8000u) ? 0xFFFFu : 0x8000u);
                if (m >= 2 && m < M2) {
                  if (pass == 0) atomicAdd(&hw[key >> 8], 1u);
                  else if ((key >> 8) == tb) atomicAdd(&hw[key & 255u], 1u);
                }
              }
            }
          }
          unsigned c0 = hw[4*lane], c1 = hw[4*lane+1], c2 = hw[4*lane+2], c3 = hw[4*lane+3];
          unsigned run = c0 + c1 + c2 + c3;
          #pragma unroll
          for (int off = 1; off < 64; off <<= 1) {
            unsigned o_ = __shfl_down(run, off, 64);
            if (lane + off < 64) run += o_;
          }
          unsigned s0 = run, s1 = run - c0, s2 = s1 - c1, s3 = s2 - c2, s4 = s3 - c3;
          int which = -1;
          if      (s0 >= k_rem && s1 < k_rem) which = 0;
          else if (s1 >= k_rem && s2 < k_rem) which = 1;
          else if (s2 >= k_rem && s3 < k_rem) which = 2;
          else if (s3 >= k_rem && s4 < k_rem) which = 3;
          unsigned long long bal = __ballot(which >= 0);
          int src = (int)__ffsll(bal) - 1;
          unsigned nxtv = (which == 0) ? s1 : (which == 1) ? s2 : (which == 2) ? s3 : s4;
          unsigned bsel = (unsigned)(4 * lane + (which < 0 ? 0 : which));
          bsel = (unsigned)__shfl((int)bsel, src, 64);
          nxtv = (unsigned)__shfl((int)nxtv, src, 64);
          if (pass == 0) tb = bsel; else thrkey = (tb << 8) | bsel;
          k_rem -= nxtv;
        }
      }

      // row max over kept values (+ anchors), on integer keys
      unsigned maxkey = 0;
      #pragma unroll
      for (int c = 0; c < 9; ++c) {
        const unsigned* pw = (const unsigned*)&rv[c];
        #pragma unroll
        for (int p2 = 0; p2 < 4; ++p2) {
          unsigned pk = pw[p2];
          int mb = c * 512 + lane * 8 + p2 * 2;
          #pragma unroll
          for (int e = 0; e < 2; ++e) {
            int m = mb + e;
            unsigned u = (e == 0) ? (pk & 0xFFFFu) : (pk >> 16);
            unsigned key = u ^ ((u & 0x8000u) ? 0xFFFFu : 0x8000u);
            bool kept = (m < 2) || (m < M2 && key >= thrkey);
            if (kept && key > maxkey) maxkey = key;
          }
        }
      }
      #pragma unroll
      for (int off = 32; off > 0; off >>= 1) {
        unsigned o_ = (unsigned)__shfl_xor((int)maxkey, off, 64);
        if (o_ > maxkey) maxkey = o_;
      }
      float lmax = bton((unsigned short)(maxkey ^ ((maxkey & 0x8000u) ? 0x8000u : 0xFFFFu)));

      // exp (kept only) + sum; pack e as bf16 into pv
      float lsum = 0.f;
      uint4 pv[9];
      #pragma unroll
      for (int c = 0; c < 9; ++c) {
        const unsigned* pw = (const unsigned*)&rv[c];
        unsigned* qv = (unsigned*)&pv[c];
        #pragma unroll
        for (int p2 = 0; p2 < 4; ++p2) {
          unsigned pk = pw[p2];
          int mb = c * 512 + lane * 8 + p2 * 2;
          unsigned outw = 0;
          #pragma unroll
          for (int e = 0; e < 2; ++e) {
            int m = mb + e;
            unsigned u = (e == 0) ? (pk & 0xFFFFu) : (pk >> 16);
            unsigned key = u ^ ((u & 0x8000u) ? 0xFFFFu : 0x8000u);
            bool kept = (m < 2) || (m < M2 && key >= thrkey);
            float ev = kept ? __expf(bton((unsigned short)u) - lmax) : 0.f;
            lsum += ev;
            outw |= ((unsigned)btrunc(ev)) << (16 * e);
          }
          qv[p2] = outw;
        }
      }
      #pragma unroll
      for (int off = 32; off > 0; off >>= 1) lsum += __shfl_xor(lsum, off, 64);
      float invZ = 1.0f / lsum;

      // normalize and write P back (9 x b128)
      #pragma unroll
      for (int c = 0; c < 9; ++c) {
        unsigned* qv = (unsigned*)&pv[c];
        #pragma unroll
        for (int p2 = 0; p2 < 4; ++p2) {
          unsigned pk = qv[p2];
          float lo = bton((unsigned short)(pk & 0xFFFFu)) * invZ;
          float hi = bton((unsigned short)(pk >> 16)) * invZ;
          qv[p2] = (unsigned)btrunc(lo) | (((unsigned)btrunc(hi)) << 16);
        }
        if (c < 8)
          *(uint4*)(dsm + r * SROWB + (((unsigned)(c * 1024 + lane * 16)) ^ swz)) = pv[c];
        else if (lane < 16)
          *(uint4*)(dsm + r * SROWB + (((unsigned)(8192 + lane * 16)) ^ swz)) = pv[8];
      }
    }
    __syncthreads();

    // ---- ph2.5: attn_mean global RMW (coalesced; block-exclusive rows) ----
    {
      const int ar = t >> 6, al = t & 63;
      const unsigned aswz = (unsigned)((ar & 7) << 4);
      for (int j = 0; j < 65; ++j) {
        int m = al + 64 * j;
        if (m < M2) {
          float p = bton(*(const unsigned short*)(dsm + ar * SROWB + ((2 * m) ^ aswz))) * 0.125f;
          size_t gi = (size_t)(n0 + ar) * M2 + m;
          if (h == 0) attn_mean_out[gi] = p;
          else        attn_mean_out[gi] += p;
        }
      }
    }

    // ---- ph3: PV = P @ V (K-split over 16 waves); P already normalized ----
    {
      const int nks = (w < 4) ? 9 : 8;
      const int ks0 = (w < 4) ? w * 9 : 36 + (w - 4) * 8;
      f32x4 o0 = {0.f,0.f,0.f,0.f}, o1 = o0, o2 = o0, o3 = o0;
      const unsigned short* Vb = Vt + (size_t)(h * HD) * MPAD;
      for (int ks = 0; ks < nks; ks++) {
        int kk = (ks0 + ks) * 32 + lg * 8;
        bf16x8 a = *(const bf16x8*)(dsm + lr * SROWB + ((2 * kk) ^ ((lr & 7) << 4)));
        bf16x8 b0 = *(const bf16x8*)(Vb + (size_t)(lr) * MPAD + kk);
        bf16x8 b1 = *(const bf16x8*)(Vb + (size_t)(16 + lr) * MPAD + kk);
        bf16x8 b2 = *(const bf16x8*)(Vb + (size_t)(32 + lr) * MPAD + kk);
        bf16x8 b3 = *(const bf16x8*)(Vb + (size_t)(48 + lr) * MPAD + kk);
        o0 = __builtin_amdgcn_mfma_f32_16x16x32_bf16(a, b0, o0, 0, 0, 0);
        o1 = __builtin_amdgcn_mfma_f32_16x16x32_bf16(a, b1, o1, 0, 0, 0);
        o2 = __builtin_amdgcn_mfma_f32_16x16x32_bf16(a, b2, o2, 0, 0, 0);
        o3 = __builtin_amdgcn_mfma_f32_16x16x32_bf16(a, b3, o3, 0, 0, 0);
      }
      __syncthreads();   // all waves done reading P (ph2.5 + MFMA)
      float* part = (float*)dsm;   // [16][16][64] = 64 KB, overlays S rows
      #pragma unroll
      for (int q = 0; q < 4; q++) {
        int row = lg * 4 + q;
        part[w * 1024 + row * 64 +      lr] = o0[q];
        part[w * 1024 + row * 64 + 16 + lr] = o1[q];
        part[w * 1024 + row * 64 + 32 + lr] = o2[q];
        part[w * 1024 + row * 64 + 48 + lr] = o3[q];
      }
      __syncthreads();
      {
        float s = 0.f;
        #pragma unroll
        for (int ww = 0; ww < 16; ++ww) s += part[ww * 1024 + t];
        aobf[(size_t)(n0 + (t >> 6)) * DIM + h * HD + (t & 63)] = btrunc(s);
      }
      // next head's post-ph0 barrier protects part reads from S overwrite
    }
  }
}

// ---------------- concat(sfbf, bf16(pj)) ----------------
__global__ __launch_bounds__(256) void cat_bf(
    const unsigned short* __restrict__ sfbf, const float* __restrict__ pj,
    unsigned short* __restrict__ cat) {
  int i4 = blockIdx.x * 256 + threadIdx.x;
  if (i4 >= (4096 * 1024) / 4) return;
  int idx = i4 * 4;
  int n = idx >> 10, c = idx & 1023;
  if (c < 512) {
    *(ushort4*)(cat + idx) = *(const ushort4*)(sfbf + (size_t)n * 512 + c);
  } else {
    float4 v = *(const float4*)(pj + (size_t)n * 512 + (c - 512));
    ushort4 o; o.x = btrunc(v.x); o.y = btrunc(v.y); o.z = btrunc(v.z); o.w = btrunc(v.w);
    *(ushort4*)(cat + idx) = o;
  }
}

// ---------------- gate, residual, RMSNorm, gate partial sums ----------------
__global__ __launch_bounds__(256) void final_kernel(
    const float* __restrict__ sf, const float* __restrict__ pj,
    const float* __restrict__ gl, const float* __restrict__ norm_w,
    float* __restrict__ outf, float* __restrict__ gpart) {
  int n = blockIdx.x, t = threadIdx.x;
  __shared__ float red[256];
  size_t base = (size_t)n * 512;
  float g0 = sigmoidf_(gl[base + t]);
  float g1 = sigmoidf_(gl[base + 256 + t]);
  float x0 = sf[base + t], x1 = sf[base + 256 + t];
  float p0 = pj[base + t], p1 = pj[base + 256 + t];
  float gr0 = x0 + g0 * p0, gr1 = x1 + g1 * p1;

  red[t] = g0 + g1;
  __syncthreads();
  for (int off = 128; off > 0; off >>= 1) {
    if (t < off) red[t] += red[t + off];
    __syncthreads();
  }
  if (t == 0) gpart[n] = red[0];
  __syncthreads();

  red[t] = gr0 * gr0 + gr1 * gr1;
  __syncthreads();
  for (int off = 128; off > 0; off >>= 1) {
    if (t < off) red[t] += red[t + off];
    __syncthreads();
  }
  float rms = rsqrtf(red[0] * (1.0f / 512.0f) + 1e-6f);
  outf[base + t] = gr0 * rms * norm_w[t];
  outf[base + 256 + t] = gr1 * rms * norm_w[256 + t];
}

__global__ __launch_bounds__(256) void gate_reduce(
    const float* __restrict__ gpart, float* __restrict__ out_scalar) {
  __shared__ float red[256];
  int t = threadIdx.x;
  float s = 0.f;
  for (int i = t; i < 4096; i += 256) s += gpart[i];
  red[t] = s;
  __syncthreads();
  for (int off = 128; off > 0; off >>= 1) {
    if (t < off) red[t] += red[t + off];
    __syncthreads();
  }
  if (t == 0) out_scalar[0] = red[0] * (1.0f / (4096.0f * 512.0f));
}

extern "C" void kernel_launch(void* const* d_in, const int* in_sizes, int n_in,
                              void* d_out, int out_size, void* d_ws, size_t ws_size,
                              hipStream_t stream) {
  const float* sf  = (const float*)d_in[0];
  const float* zp  = (const float*)d_in[1];
  const float* zs  = (const float*)d_in[2];
  const float* Wq  = (const float*)d_in[3];
  const float* Wk  = (const float*)d_in[4];
  const float* Wv  = (const float*)d_in[5];
  const float* Wg  = (const float*)d_in[6];
  const float* bg  = (const float*)d_in[7];
  const float* Wag = (const float*)d_in[8];
  const float* bag = (const float*)d_in[9];
  const float* nw  = (const float*)d_in[10];
  const float* Wo  = (const float*)d_in[11];
  const float* bo  = (const float*)d_in[12];

  float* out  = (float*)d_out;
  float* outF = out + OUT_F;
  float* outR = out + OUT_R;
  float* outG = out + OUT_G;
  float* outA = out + OUT_A;

  // workspace layout (bytes)
  char* W = (char*)d_ws;
  float*          regime  = (float*)(W + 0);                 // 2048
  float*          gpart   = (float*)(W + 2048);              // 16384
  unsigned short* sfbf    = (unsigned short*)(W + 18432);    // 4,194,304
  unsigned short* nodesbf = (unsigned short*)(W + 4212736);  // 4,196,352
  unsigned short* Qbf     = (unsigned short*)(W + 8409088);  // 4,194,304
  unsigned short* Kbf     = (unsigned short*)(W + 12603392); // 4,325,376 (4224 rows)
  unsigned short* Vt      = (unsigned short*)(W + 16928768); // 4,325,376 (512 x 4224)
  unsigned short* aobf    = (unsigned short*)(W + 21254144); // 4,194,304
  unsigned short* catbf   = (unsigned short*)(W + 25448448); // 8,388,608
  unsigned short* Wqbf    = (unsigned short*)(W + 33837056); // 524,288
  unsigned short* Wkbf    = (unsigned short*)(W + 34361344); // 524,288
  unsigned short* Wvbf    = (unsigned short*)(W + 34885632); // 524,288
  unsigned short* Wobf    = (unsigned short*)(W + 35409920); // 524,288
  unsigned short* Wagbf   = (unsigned short*)(W + 35934208); // 1,048,576
  float*          pj      = (float*)(W + 36982784);          // 8,388,608 -> 45,371,392
  float*          gl      = (float*)(W + 4212736);           // alias over nodesbf+Qbf (dead by then)

  hipFuncSetAttribute((const void*)fused_attn,
                      hipFuncAttributeMaxDynamicSharedMemorySize, SMEMSZ);

  // --- small prep ---
  regime_kernel<<<1, 256, 0, stream>>>(zp, zs, Wg, bg, regime);
  conv_bf<<<2048, 256, 0, stream>>>(sf, sfbf, 524288);
  build_nodes_bf<<<2049, 256, 0, stream>>>(zp, zs, sf, nodesbf);
  conv_bf<<<256, 256, 0, stream>>>(Wq, Wqbf, 65536);
  conv_bf<<<256, 256, 0, stream>>>(Wk, Wkbf, 65536);
  conv_bf<<<256, 256, 0, stream>>>(Wv, Wvbf, 65536);
  conv_bf<<<256, 256, 0, stream>>>(Wo, Wobf, 65536);
  conv_bf<<<512, 256, 0, stream>>>(Wag, Wagbf, 131072);
  hipMemsetAsync(Kbf, 0, 4325376, stream);
  hipMemsetAsync(Vt, 0, 4325376, stream);

  // --- projections (bf16 MFMA) ---
  gemm_bf16<<<dim3(4, 32), 256, 0, stream>>>(sfbf, Wqbf, nullptr, regime, nullptr, Qbf,
                                             4096, 512, 512, 512, 512, 512, 1.0f, 1);
  gemm_bf16<<<dim3(4, 33), 256, 0, stream>>>(nodesbf, Wkbf, nullptr, nullptr, nullptr, Kbf,
                                             M2, 512, 512, 512, 512, 512, 1.0f, 1);
  gemm_bf16<<<dim3(4, 33), 256, 0, stream>>>(nodesbf, Wvbf, nullptr, nullptr, nullptr, Vt,
                                             M2, 512, 512, 512, 512, MPAD, 1.0f, 2);

  // --- raw_scores = (Q @ K^T) * (0.125/8) over full 512 dims ---
  gemm_bf16<<<dim3(33, 32), 256, 0, stream>>>(Qbf, Kbf, nullptr, nullptr, outR, nullptr,
                                              4096, M2, 512, 512, 512, M2, 0.015625f, 0);

  // --- fused attention (256 blocks, 1024 threads, no atomics) ---
  fused_attn<<<256, 1024, SMEMSZ, stream>>>(Qbf, Kbf, Vt, aobf, outA);

  // --- output projection + gate + final ---
  gemm_bf16<<<dim3(4, 32), 256, 0, stream>>>(aobf, Wobf, bo, nullptr, pj, nullptr,
                                             4096, 512, 512, 512, 512, 512, 1.0f, 0);
  cat_bf<<<4096, 256, 0, stream>>>(sfbf, pj, catbf);
  gemm_bf16<<<dim3(4, 32), 256, 0, stream>>>(catbf, Wagbf, bag, nullptr, gl, nullptr,
                                             4096, 512, 1024, 1024, 1024, 512, 1.0f, 0);
  final_kernel<<<4096, 256, 0, stream>>>(sf, pj, gl, nw, outF, gpart);
  gate_reduce<<<1, 256, 0, stream>>>(gpart, outG);
}